// Round 8
// baseline (135.303 us; speedup 1.0000x reference)
//
#include <hip/hip_runtime.h>

// Deformable conv, B=16 C=64 H=W=64, COUT=128, K=3 s=1 p=1 d=1.
// R8: barrier-free wave-tile restructure of deform_main.
//   Wave = 16 px x 128 oc. Producer mapping == A-fragment mapping:
//   lane l samples px = px0+(l&15), channels c0=(l>>4)*8 (+32 for kstep1)
//   -> bilinear result goes STRAIGHT into the lane's A-frag registers.
//   No col LDS, no cross-lane, no barriers in the K-loop. 4096 independent
//   waves (16/CU) hide gather latency by TLP (R5/R6 showed intra-wave
//   pipelining can't; R7 probe showed the gather stream alone is ~10 µs).
//   B-frags (8 octiles x 2 ksteps) JIT-loaded from L2-resident wf per kk.
//   Epilogue: per-octile 16x16 LDS transpose (wave-private) -> 64B stores.

typedef short bf8 __attribute__((ext_vector_type(8)));   // 8 bf16 (4 VGPR)
typedef float f32x4 __attribute__((ext_vector_type(4)));
typedef unsigned short u16;
typedef u16 u16x8 __attribute__((ext_vector_type(8)));

__device__ inline u16 f2bf(float f) {                    // RNE f32 -> bf16
    unsigned u = __float_as_uint(f);
    return (u16)((u + 0x7FFFu + ((u >> 16) & 1u)) >> 16);
}
__device__ inline float bf2f(u16 v) {
    return __uint_as_float(((unsigned)v) << 16);
}

__global__ __launch_bounds__(256) void transpose_x_kernel(const float* __restrict__ x,
                                                          u16* __restrict__ xtb) {
    __shared__ float tile[64][65];
    int bid = blockIdx.x;            // b*64 + y
    int t = threadIdx.x;
    int b = bid >> 6, y = bid & 63;
    const float* xb = x + (size_t)b * 262144 + (size_t)y * 64;  // x[b][0][y][0]
#pragma unroll
    for (int it = 0; it < 16; ++it) {            // 16*256 = 4096 = 64c*64w
        int idx = t + it * 256;
        int c = idx >> 6, w = idx & 63;
        tile[c][w] = xb[(size_t)c * 4096 + w];
    }
    __syncthreads();
    unsigned* dst = (unsigned*)(xtb + (size_t)bid * 4096);   // xtb[b][y][w][c]
#pragma unroll
    for (int it = 0; it < 8; ++it) {             // 2 c's per thread -> 4B stores
        int p = t + it * 256;                    // w = p>>5, c0 = (p&31)*2
        int w = p >> 5, c0 = (p & 31) * 2;
        unsigned lo = f2bf(tile[c0][w]);
        unsigned hi = f2bf(tile[c0 + 1][w]);
        dst[p] = lo | (hi << 16);
    }
}

// wf[kk][octile(8)][kstep(2)][lane(64)][i(8)] = bf16(weight[oc][c][kk])
//   oc = octile*16 + (lane&15); c = kstep*32 + (lane>>4)*8 + i
__global__ __launch_bounds__(256) void build_wfrag(const float* __restrict__ wgt,
                                                   short* __restrict__ wf) {
    int idx = blockIdx.x * 256 + threadIdx.x;    // 73728 total
    int i = idx & 7;
    int lane = (idx >> 3) & 63;
    int ks = (idx >> 9) & 1;
    int oct = (idx >> 10) & 7;
    int kk = idx >> 13;
    int oc = oct * 16 + (lane & 15);
    int c = ks * 32 + (lane >> 4) * 8 + i;
    wf[idx] = (short)f2bf(wgt[((size_t)oc * 64 + c) * 9 + kk]);
}

__global__ __launch_bounds__(64, 4) void deform_main(const u16* __restrict__ xtb,
                                                     const float* __restrict__ offset,
                                                     const short* __restrict__ wf,
                                                     float* __restrict__ out) {
    __shared__ float off_lds[288];               // 18 ch x 16 px
    __shared__ __align__(16) float eps[320];     // 16 oc x 20 (stride 20 f32 = 80B, 16B-aligned)

    // XCD-aware swizzle: 4096 blocks, XCD k owns wgid [512k, 512k+512) = images {2k,2k+1}
    int wg = blockIdx.x;
    int wgid = (wg & 7) * 512 + (wg >> 3);
    int b = wgid >> 8, ho = (wgid >> 2) & 63, px0 = (wgid & 3) << 4;
    int l = threadIdx.x;
    const int pxl = l & 15;          // lane's px within the 16-px tile
    const int c0 = (l >> 4) * 8;     // lane's channel octet base

    // stage this tile's offsets: offset[b][ch][ho][px0+px_local]
    {
        const float* ob = offset + (size_t)b * 73728 + ho * 64 + px0;
        for (int idx = l; idx < 288; idx += 64)
            off_lds[idx] = ob[(idx >> 4) * 4096 + (idx & 15)];
    }
    __syncthreads();                 // single wave: near-free

    f32x4 acc[8];
#pragma unroll
    for (int o = 0; o < 8; ++o) acc[o] = (f32x4)0.f;

    const u16* xb = xtb + (size_t)b * 262144;    // xtb[b][y][x][c] bf16
    const float fpx = (float)(px0 + pxl - 1);

    for (int kk = 0; kk < 9; ++kk) {
        int ky = kk / 3, kx = kk - ky * 3;
        // sample point for THIS lane's px
        float py = off_lds[(2 * kk) * 16 + pxl] + (float)(ho - 1 + ky);
        float sx = off_lds[(2 * kk + 1) * 16 + pxl] + fpx + (float)kx;
        float y0f = floorf(py), x0f = floorf(sx);
        float ly = py - y0f, lx = sx - x0f;
        int y0 = (int)y0f, x0 = (int)x0f;
        int y1 = y0 + 1, x1 = x0 + 1;
        float w00 = (1.f - ly) * (1.f - lx), w01 = (1.f - ly) * lx;
        float w10 = ly * (1.f - lx), w11 = ly * lx;
        bool vy0 = (y0 >= 0) & (y0 < 64), vy1 = (y1 >= 0) & (y1 < 64);
        bool vx0 = (x0 >= 0) & (x0 < 64), vx1 = (x1 >= 0) & (x1 < 64);
        if (!(vy0 & vx0)) w00 = 0.f;
        if (!(vy0 & vx1)) w01 = 0.f;
        if (!(vy1 & vx0)) w10 = 0.f;
        if (!(vy1 & vx1)) w11 = 0.f;
        int y0c = min(max(y0, 0), 63), y1c = min(max(y1, 0), 63);
        int x0c = min(max(x0, 0), 63), x1c = min(max(x1, 0), 63);

        // 8 x 16B gathers: 4 corners x 2 ksteps (c0 and c0+32)
        const u16* p00 = xb + ((y0c * 64 + x0c) * 64) + c0;
        const u16* p01 = xb + ((y0c * 64 + x1c) * 64) + c0;
        const u16* p10 = xb + ((y1c * 64 + x0c) * 64) + c0;
        const u16* p11 = xb + ((y1c * 64 + x1c) * 64) + c0;
        u16x8 g00a = *(const u16x8*)p00,        g00b = *(const u16x8*)(p00 + 32);
        u16x8 g01a = *(const u16x8*)p01,        g01b = *(const u16x8*)(p01 + 32);
        u16x8 g10a = *(const u16x8*)p10,        g10b = *(const u16x8*)(p10 + 32);
        u16x8 g11a = *(const u16x8*)p11,        g11b = *(const u16x8*)(p11 + 32);

        // bilinear -> A-fragments IN PLACE (lane mapping == MFMA A layout)
        bf8 af0, af1;
#pragma unroll
        for (int i = 0; i < 8; ++i) {
            float ra = w00 * bf2f(g00a[i]) + w01 * bf2f(g01a[i]) +
                       w10 * bf2f(g10a[i]) + w11 * bf2f(g11a[i]);
            af0[i] = (short)f2bf(ra);
            float rb = w00 * bf2f(g00b[i]) + w01 * bf2f(g01b[i]) +
                       w10 * bf2f(g10b[i]) + w11 * bf2f(g11b[i]);
            af1[i] = (short)f2bf(rb);
        }

        // B-fragments for all 8 octiles x 2 ksteps (issued after interp so
        // gather regs are dead -> VGPR peak stays under the 128 cap)
        const short* wk = wf + (size_t)kk * 8192;
        bf8 bv[16];
#pragma unroll
        for (int o = 0; o < 8; ++o) {
            bv[2 * o]     = *(const bf8*)(wk + ((o * 2 + 0) * 64 + l) * 8);
            bv[2 * o + 1] = *(const bf8*)(wk + ((o * 2 + 1) * 64 + l) * 8);
        }
        // 16 MFMAs; ksi0 sweep then ksi1 sweep (dep distance 8 on each acc)
#pragma unroll
        for (int o = 0; o < 8; ++o)
            acc[o] = __builtin_amdgcn_mfma_f32_16x16x32_bf16(af0, bv[2 * o], acc[o], 0, 0, 0);
#pragma unroll
        for (int o = 0; o < 8; ++o)
            acc[o] = __builtin_amdgcn_mfma_f32_16x16x32_bf16(af1, bv[2 * o + 1], acc[o], 0, 0, 0);
    }

    // ---- epilogue: D layout col(lane&15)=oc, row=(lane>>4)*4+r = px_local.
    //      Per octile: wave-private 16x16 LDS transpose -> 64B stores. ----
    float* outb = out + (size_t)b * 524288 + ho * 64 + px0;  // out[b][0][ho][px0]
    const int ocw = l & 15, hiw = (l >> 4) * 4;
    const int ocr = l >> 2, ch4 = (l & 3) * 4;
#pragma unroll
    for (int o = 0; o < 8; ++o) {
#pragma unroll
        for (int r = 0; r < 4; ++r)
            eps[ocw * 20 + hiw + r] = acc[o][r];
        __syncthreads();
        f32x4 v = *(const f32x4*)(eps + ocr * 20 + ch4);
        *(f32x4*)(outb + (size_t)(o * 16 + ocr) * 4096 + ch4) = v;
        __syncthreads();
    }
}

extern "C" void kernel_launch(void* const* d_in, const int* in_sizes, int n_in,
                              void* d_out, int out_size, void* d_ws, size_t ws_size,
                              hipStream_t stream) {
    const float* x = (const float*)d_in[0];
    const float* offset = (const float*)d_in[1];
    const float* wgt = (const float*)d_in[2];
    float* out = (float*)d_out;
    u16* xtb = (u16*)d_ws;                              // 8.39 MB bf16 NHWC
    short* wfrag = (short*)(xtb + (size_t)16 * 64 * 64 * 64);  // 73728 bf16

    hipLaunchKernelGGL(transpose_x_kernel, dim3(1024), dim3(256), 0, stream, x, xtb);
    hipLaunchKernelGGL(build_wfrag, dim3(288), dim3(256), 0, stream, wgt, wfrag);
    hipLaunchKernelGGL(deform_main, dim3(4096), dim3(64), 0, stream, xtb, offset, wfrag, out);
}

// Round 9
// 132.809 us; speedup vs baseline: 1.0188x; 1.0188x over previous
//
#include <hip/hip_runtime.h>

// Deformable conv, B=16 C=64 H=W=64, COUT=128, K=3 s=1 p=1 d=1.
// R9: R8 wave-tile structure + FORCED B-load batching.
//   R8 failed because the compiler targeted 64 VGPR (8 waves/SIMD) and sank
//   each B-fragment load to just before its MFMA -> 16 serialized L2-latency
//   stalls per kk (MfmaUtil 5.5%). Here B loads come in two batches of 8
//   pinned with sched_barrier(0); peak ~110 VGPR fits launch_bounds(64,4)'s
//   128 cap, so the compiler must keep the batch resident.
//   Wave = 16 px x 128 oc; bilinear lands directly in A-frag registers;
//   no col-LDS, no K-loop barriers; 4096 independent waves.

typedef short bf8 __attribute__((ext_vector_type(8)));   // 8 bf16 (4 VGPR)
typedef float f32x4 __attribute__((ext_vector_type(4)));
typedef unsigned short u16;
typedef u16 u16x8 __attribute__((ext_vector_type(8)));

__device__ inline u16 f2bf(float f) {                    // RNE f32 -> bf16
    unsigned u = __float_as_uint(f);
    return (u16)((u + 0x7FFFu + ((u >> 16) & 1u)) >> 16);
}
__device__ inline float bf2f(u16 v) {
    return __uint_as_float(((unsigned)v) << 16);
}

__global__ __launch_bounds__(256) void transpose_x_kernel(const float* __restrict__ x,
                                                          u16* __restrict__ xtb) {
    __shared__ float tile[64][65];
    int bid = blockIdx.x;            // b*64 + y
    int t = threadIdx.x;
    int b = bid >> 6, y = bid & 63;
    const float* xb = x + (size_t)b * 262144 + (size_t)y * 64;  // x[b][0][y][0]
#pragma unroll
    for (int it = 0; it < 16; ++it) {            // 16*256 = 4096 = 64c*64w
        int idx = t + it * 256;
        int c = idx >> 6, w = idx & 63;
        tile[c][w] = xb[(size_t)c * 4096 + w];
    }
    __syncthreads();
    unsigned* dst = (unsigned*)(xtb + (size_t)bid * 4096);   // xtb[b][y][w][c]
#pragma unroll
    for (int it = 0; it < 8; ++it) {             // 2 c's per thread -> 4B stores
        int p = t + it * 256;                    // w = p>>5, c0 = (p&31)*2
        int w = p >> 5, c0 = (p & 31) * 2;
        unsigned lo = f2bf(tile[c0][w]);
        unsigned hi = f2bf(tile[c0 + 1][w]);
        dst[p] = lo | (hi << 16);
    }
}

// wf[kk][octile(8)][kstep(2)][lane(64)][i(8)] = bf16(weight[oc][c][kk])
//   oc = octile*16 + (lane&15); c = kstep*32 + (lane>>4)*8 + i
__global__ __launch_bounds__(256) void build_wfrag(const float* __restrict__ wgt,
                                                   short* __restrict__ wf) {
    int idx = blockIdx.x * 256 + threadIdx.x;    // 73728 total
    int i = idx & 7;
    int lane = (idx >> 3) & 63;
    int ks = (idx >> 9) & 1;
    int oct = (idx >> 10) & 7;
    int kk = idx >> 13;
    int oc = oct * 16 + (lane & 15);
    int c = ks * 32 + (lane >> 4) * 8 + i;
    wf[idx] = (short)f2bf(wgt[((size_t)oc * 64 + c) * 9 + kk]);
}

__global__ __launch_bounds__(64, 4) void deform_main(const u16* __restrict__ xtb,
                                                     const float* __restrict__ offset,
                                                     const short* __restrict__ wf,
                                                     float* __restrict__ out) {
    __shared__ float off_lds[288];               // 18 ch x 16 px
    __shared__ __align__(16) float eps[320];     // 16 oc x 20 f32 (80B stride)

    // XCD-aware swizzle: 4096 blocks, XCD k owns wgid [512k,512k+512) = images {2k,2k+1}
    int wg = blockIdx.x;
    int wgid = (wg & 7) * 512 + (wg >> 3);
    int b = wgid >> 8, ho = (wgid >> 2) & 63, px0 = (wgid & 3) << 4;
    int l = threadIdx.x;
    const int pxl = l & 15;          // lane's px within the 16-px tile
    const int c0 = (l >> 4) * 8;     // lane's channel octet base

    // stage this tile's offsets: offset[b][ch][ho][px0+px_local]
    {
        const float* ob = offset + (size_t)b * 73728 + ho * 64 + px0;
        for (int idx = l; idx < 288; idx += 64)
            off_lds[idx] = ob[(idx >> 4) * 4096 + (idx & 15)];
    }
    __syncthreads();                 // single wave: near-free

    f32x4 acc[8];
#pragma unroll
    for (int o = 0; o < 8; ++o) acc[o] = (f32x4)0.f;

    const u16* xb = xtb + (size_t)b * 262144;    // xtb[b][y][x][c] bf16
    const float fpx = (float)(px0 + pxl - 1);

    for (int kk = 0; kk < 9; ++kk) {
        int ky = kk / 3, kx = kk - ky * 3;
        float py = off_lds[(2 * kk) * 16 + pxl] + (float)(ho - 1 + ky);
        float sx = off_lds[(2 * kk + 1) * 16 + pxl] + fpx + (float)kx;
        float y0f = floorf(py), x0f = floorf(sx);
        float ly = py - y0f, lx = sx - x0f;
        int y0 = (int)y0f, x0 = (int)x0f;
        int y1 = y0 + 1, x1 = x0 + 1;
        float w00 = (1.f - ly) * (1.f - lx), w01 = (1.f - ly) * lx;
        float w10 = ly * (1.f - lx), w11 = ly * lx;
        bool vy0 = (y0 >= 0) & (y0 < 64), vy1 = (y1 >= 0) & (y1 < 64);
        bool vx0 = (x0 >= 0) & (x0 < 64), vx1 = (x1 >= 0) & (x1 < 64);
        if (!(vy0 & vx0)) w00 = 0.f;
        if (!(vy0 & vx1)) w01 = 0.f;
        if (!(vy1 & vx0)) w10 = 0.f;
        if (!(vy1 & vx1)) w11 = 0.f;
        int y0c = min(max(y0, 0), 63), y1c = min(max(y1, 0), 63);
        int x0c = min(max(x0, 0), 63), x1c = min(max(x1, 0), 63);

        // 8 x 16B gathers: 4 corners x 2 ksteps (c0 and c0+32)
        const u16* p00 = xb + ((y0c * 64 + x0c) * 64) + c0;
        const u16* p01 = xb + ((y0c * 64 + x1c) * 64) + c0;
        const u16* p10 = xb + ((y1c * 64 + x0c) * 64) + c0;
        const u16* p11 = xb + ((y1c * 64 + x1c) * 64) + c0;
        u16x8 g00a = *(const u16x8*)p00,        g00b = *(const u16x8*)(p00 + 32);
        u16x8 g01a = *(const u16x8*)p01,        g01b = *(const u16x8*)(p01 + 32);
        u16x8 g10a = *(const u16x8*)p10,        g10b = *(const u16x8*)(p10 + 32);
        u16x8 g11a = *(const u16x8*)p11,        g11b = *(const u16x8*)(p11 + 32);

        // bilinear -> A-fragments IN PLACE (lane mapping == MFMA A layout)
        bf8 af0, af1;
#pragma unroll
        for (int i = 0; i < 8; ++i) {
            float ra = w00 * bf2f(g00a[i]) + w01 * bf2f(g01a[i]) +
                       w10 * bf2f(g10a[i]) + w11 * bf2f(g11a[i]);
            af0[i] = (short)f2bf(ra);
            float rb = w00 * bf2f(g00b[i]) + w01 * bf2f(g01b[i]) +
                       w10 * bf2f(g10b[i]) + w11 * bf2f(g11b[i]);
            af1[i] = (short)f2bf(rb);
        }

        const short* wk = wf + (size_t)kk * 8192;

        // ---- B batch 1: ks0 for all 8 octiles (8 x 16B, batched) ----
        bf8 bv0[8];
#pragma unroll
        for (int o = 0; o < 8; ++o)
            bv0[o] = *(const bf8*)(wk + ((o * 2 + 0) * 64 + l) * 8);
        __builtin_amdgcn_sched_barrier(0);   // loads stay above; MFMAs below
#pragma unroll
        for (int o = 0; o < 8; ++o)
            acc[o] = __builtin_amdgcn_mfma_f32_16x16x32_bf16(af0, bv0[o], acc[o], 0, 0, 0);

        // ---- B batch 2: ks1 (may interleave into batch-1 MFMAs) ----
        bf8 bv1[8];
#pragma unroll
        for (int o = 0; o < 8; ++o)
            bv1[o] = *(const bf8*)(wk + ((o * 2 + 1) * 64 + l) * 8);
        __builtin_amdgcn_sched_barrier(0);
#pragma unroll
        for (int o = 0; o < 8; ++o)
            acc[o] = __builtin_amdgcn_mfma_f32_16x16x32_bf16(af1, bv1[o], acc[o], 0, 0, 0);
    }

    // ---- epilogue: D layout col(lane&15)=oc, row=(lane>>4)*4+r = px_local.
    //      Per octile: wave-private 16x16 LDS transpose -> 64B stores. ----
    float* outb = out + (size_t)b * 524288 + ho * 64 + px0;  // out[b][0][ho][px0]
    const int ocw = l & 15, hiw = (l >> 4) * 4;
    const int ocr = l >> 2, ch4 = (l & 3) * 4;
#pragma unroll
    for (int o = 0; o < 8; ++o) {
#pragma unroll
        for (int r = 0; r < 4; ++r)
            eps[ocw * 20 + hiw + r] = acc[o][r];
        __syncthreads();
        f32x4 v = *(const f32x4*)(eps + ocr * 20 + ch4);
        *(f32x4*)(outb + (size_t)(o * 16 + ocr) * 4096 + ch4) = v;
        __syncthreads();
    }
}

extern "C" void kernel_launch(void* const* d_in, const int* in_sizes, int n_in,
                              void* d_out, int out_size, void* d_ws, size_t ws_size,
                              hipStream_t stream) {
    const float* x = (const float*)d_in[0];
    const float* offset = (const float*)d_in[1];
    const float* wgt = (const float*)d_in[2];
    float* out = (float*)d_out;
    u16* xtb = (u16*)d_ws;                              // 8.39 MB bf16 NHWC
    short* wfrag = (short*)(xtb + (size_t)16 * 64 * 64 * 64);  // 73728 bf16

    hipLaunchKernelGGL(transpose_x_kernel, dim3(1024), dim3(256), 0, stream, x, xtb);
    hipLaunchKernelGGL(build_wfrag, dim3(288), dim3(256), 0, stream, wgt, wfrag);
    hipLaunchKernelGGL(deform_main, dim3(4096), dim3(64), 0, stream, xtb, offset, wfrag, out);
}